// Round 10
// baseline (935.189 us; speedup 1.0000x reference)
//
#include <hip/hip_runtime.h>
#include <hip/hip_cooperative_groups.h>

namespace cg = cooperative_groups;

#define DD 512
#define MROWS 384            // 4 batches * 96 nodes
#define EPSF 1e-5f
#define INVN (1.0f / 96.0f)
#define GBLK 384             // 384 blocks x 256 thr = 1536 waves (1.5 blk/CU)

typedef short short8v __attribute__((ext_vector_type(8)));
typedef float f32x4   __attribute__((ext_vector_type(4)));

// round-to-nearest-even f32 -> bf16 (raw ushort)
static __device__ __forceinline__ unsigned short f2bf(float x) {
    union { float f; unsigned int u; } v; v.f = x;
    unsigned int r = v.u + 0x7fffu + ((v.u >> 16) & 1u);
    return (unsigned short)(r >> 16);
}

struct GnnParams {
    const float *h0, *adj, *W1a, *W1b, *b1, *W2, *b2, *gamma, *beta;
    float *out;
    // never-rewrite buffers: each written by exactly one phase-instance
    unsigned short *WT, *H0bf, *H1bf, *S0, *S1;
    float *A0, *B0, *A1, *B1, *U0, *U1, *H1, *CNT;
};

// agent-scope release/acquire around the grid barrier (R8-proven codegen;
// R9 showed explicit wbl2/inv asm is redundant — identical output).
#define GSYNC() do { __threadfence(); grid.sync(); __threadfence(); } while (0)

__global__ __launch_bounds__(256) void gnn_fused(GnnParams P)
{
    cg::grid_group grid = cg::this_grid();
    const int tid  = threadIdx.x;
    const int bid  = blockIdx.x;
    const int lane = tid & 63;
    const int wv   = __builtin_amdgcn_readfirstlane(tid >> 6);
    const int gw   = bid * 4 + wv;            // global wave id (0..1535)

    __shared__ float tsh[32][33];

    // ---- P0a: transpose+convert 6 weight mats -> bf16 [n][k] (1536 tiles) ----
    {
        const int tx = tid & 31, ty = tid >> 5;
        for (int it = bid; it < 1536; it += GBLK) {      // 4 tiles per block
            const int z  = it >> 8;                      // 0..5 = l*3 + w
            const int r0 = ((it >> 4) & 15) * 32;
            const int c0 = (it & 15) * 32;
            const int l = z / 3, w = z % 3;
            const float* __restrict__ src =
                (w == 0 ? P.W1a : (w == 1 ? P.W1b : P.W2)) + (size_t)l * DD * DD;
            unsigned short* __restrict__ dst = P.WT + (size_t)z * DD * DD;
#pragma unroll
            for (int i = 0; i < 4; ++i)
                tsh[ty + 8 * i][tx] = src[(size_t)(r0 + ty + 8 * i) * DD + c0 + tx];
            __syncthreads();
#pragma unroll
            for (int i = 0; i < 4; ++i)
                dst[(size_t)(c0 + ty + 8 * i) * DD + r0 + tx] = f2bf(tsh[tx][ty + 8 * i]);
            __syncthreads();
        }
    }
    // ---- P0b: h0 -> bf16 (24576 x 8-float items) ----
    {
        const int i = bid * 256 + tid;
        if (i < MROWS * DD / 8) {
            const float4 x0 = *(const float4*)(P.h0 + (size_t)i * 8);
            const float4 x1 = *(const float4*)(P.h0 + (size_t)i * 8 + 4);
            uint4 u;
            u.x = (unsigned)f2bf(x0.x) | ((unsigned)f2bf(x0.y) << 16);
            u.y = (unsigned)f2bf(x0.z) | ((unsigned)f2bf(x0.w) << 16);
            u.z = (unsigned)f2bf(x1.x) | ((unsigned)f2bf(x1.y) << 16);
            u.w = (unsigned)f2bf(x1.z) | ((unsigned)f2bf(x1.w) << 16);
            *(uint4*)(P.H0bf + (size_t)i * 8) = u;
        }
    }
    // ---- P0c: cnt[r] = sum_j mask[r,j]  (layer-invariant; one wave/row) ----
    if (gw < MROWS) {
        const float* mrow = P.adj + (size_t)gw * 96;
        float v = mrow[lane];
        if (lane < 32) v += mrow[64 + lane];
#pragma unroll
        for (int off = 32; off > 0; off >>= 1) v += __shfl_xor(v, off);
        if (lane == 0) P.CNT[gw] = v;
    }
    GSYNC();

    for (int l = 0; l < 2; ++l) {
        const unsigned short* __restrict__ WaT = P.WT + (size_t)(l * 3 + 0) * DD * DD;
        const unsigned short* __restrict__ WbT = P.WT + (size_t)(l * 3 + 1) * DD * DD;
        const unsigned short* __restrict__ W2T = P.WT + (size_t)(l * 3 + 2) * DD * DD;
        const float* b1l = P.b1 + (size_t)l * DD;
        const float* b2l = P.b2 + (size_t)l * DD;
        // per-layer fresh buffers (never rewritten within the kernel)
        const unsigned short* __restrict__ Hbf = l ? P.H1bf : P.H0bf;
        float* __restrict__ A  = l ? P.A1 : P.A0;
        float* __restrict__ Bb = l ? P.B1 : P.B0;
        unsigned short* __restrict__ S = l ? P.S1 : P.S0;
        float* __restrict__ U  = l ? P.U1 : P.U0;
        const float* __restrict__ hin = l ? P.H1 : P.h0;
        float* __restrict__ hout = l ? P.out : P.H1;
        unsigned short* __restrict__ hbf_out = l ? (unsigned short*)0 : P.H1bf;

        // ---- P1: A = Hbf@Wa + b1 ; Bb = Hbf@Wb  (1536 wave-tiles 16x16) ----
        if (gw < 1536) {
            const int isB = gw >= 768;
            const int t   = gw - (isB ? 768 : 0);   // FIX: 768 is not pow2; '&767' was wrong
            const int m0  = (t >> 5) * 16;
            const int n0  = (t & 31) * 16;
            const int lo = lane & 15, hi = lane >> 4;
            const unsigned short* ap = Hbf + (size_t)(m0 + lo) * DD + 8 * hi;
            const unsigned short* bp = (isB ? WbT : WaT) + (size_t)(n0 + lo) * DD + 8 * hi;
            f32x4 acc = {0.f, 0.f, 0.f, 0.f};
#pragma unroll
            for (int k0 = 0; k0 < DD; k0 += 32)
                acc = __builtin_amdgcn_mfma_f32_16x16x32_bf16(
                    *(const short8v*)(ap + k0), *(const short8v*)(bp + k0), acc, 0, 0, 0);
            const int col = n0 + lo;
            const float bias = isB ? 0.f : b1l[col];
            float* __restrict__ outp = isB ? Bb : A;
            const int rb = m0 + 4 * hi;
#pragma unroll
            for (int i = 0; i < 4; ++i)
                outp[(size_t)(rb + i) * DD + col] = acc[i] + bias;
        }
        GSYNC();

        // ---- P2: S[b,i,d] = sum_j mask*relu(A + Bb) -> bf16 (1536 units) ----
        if (gw < 1536) {
            const int b   = gw / 384;
            const int rem = gw - b * 384;
            const int i0  = (rem >> 3) * 2;
            const int d   = (rem & 7) * 64 + lane;
            const int rb  = b * 96 + i0;
            const float a0 = A[(size_t)rb * DD + d];
            const float a1 = A[(size_t)(rb + 1) * DD + d];
            const float* __restrict__ mp  = P.adj + (size_t)rb * 96;
            const float* __restrict__ bbp = Bb + (size_t)b * 96 * DD + d;
            float s0 = 0.f, s1 = 0.f;
#pragma unroll 8
            for (int j = 0; j < 96; ++j) {
                const float bv = bbp[(size_t)j * DD];
                s0 = fmaf(mp[j],      fmaxf(a0 + bv, 0.f), s0);
                s1 = fmaf(mp[96 + j], fmaxf(a1 + bv, 0.f), s1);
            }
            S[(size_t)rb * DD + d]       = f2bf(s0);
            S[(size_t)(rb + 1) * DD + d] = f2bf(s1);
        }
        GSYNC();

        // ---- P3: U = hin + INVN*(S@W2 + cnt*b2)  (768 wave-tiles) ----
        if (gw < 768) {
            const int m0 = (gw >> 5) * 16;
            const int n0 = (gw & 31) * 16;
            const int lo = lane & 15, hi = lane >> 4;
            const unsigned short* ap = S + (size_t)(m0 + lo) * DD + 8 * hi;
            const unsigned short* bp = W2T + (size_t)(n0 + lo) * DD + 8 * hi;
            f32x4 acc = {0.f, 0.f, 0.f, 0.f};
#pragma unroll
            for (int k0 = 0; k0 < DD; k0 += 32)
                acc = __builtin_amdgcn_mfma_f32_16x16x32_bf16(
                    *(const short8v*)(ap + k0), *(const short8v*)(bp + k0), acc, 0, 0, 0);
            const int col = n0 + lo;
            const float b2c = b2l[col];
            const int rb = m0 + 4 * hi;
#pragma unroll
            for (int i = 0; i < 4; ++i) {
                const int r = rb + i;
                U[(size_t)r * DD + col] =
                    hin[(size_t)r * DD + col] + INVN * acc[i] + (P.CNT[r] * INVN) * b2c;
            }
        }
        GSYNC();

        // ---- P4: LayerNorm (one wave per row, shfl-only) + bf16 emit ----
        if (gw < MROWS) {
            const float* up = U + (size_t)gw * DD + lane * 8;
            const float4 x0 = *(const float4*)up;
            const float4 x1 = *(const float4*)(up + 4);
            float s = x0.x + x0.y + x0.z + x0.w + x1.x + x1.y + x1.z + x1.w;
#pragma unroll
            for (int off = 32; off > 0; off >>= 1) s += __shfl_xor(s, off);
            const float mu = s * (1.0f / 512.0f);
            const float d0 = x0.x - mu, d1 = x0.y - mu, d2 = x0.z - mu, d3 = x0.w - mu;
            const float d4 = x1.x - mu, d5 = x1.y - mu, d6 = x1.z - mu, d7 = x1.w - mu;
            float q = d0*d0 + d1*d1 + d2*d2 + d3*d3 + d4*d4 + d5*d5 + d6*d6 + d7*d7;
#pragma unroll
            for (int off = 32; off > 0; off >>= 1) q += __shfl_xor(q, off);
            const float rs = rsqrtf(q * (1.0f / 512.0f) + EPSF);

            const float4 g0 = *(const float4*)(P.gamma + lane * 8);
            const float4 g1 = *(const float4*)(P.gamma + lane * 8 + 4);
            const float4 t0 = *(const float4*)(P.beta + lane * 8);
            const float4 t1 = *(const float4*)(P.beta + lane * 8 + 4);
            float y0 = d0*rs*g0.x + t0.x, y1 = d1*rs*g0.y + t0.y;
            float y2 = d2*rs*g0.z + t0.z, y3 = d3*rs*g0.w + t0.w;
            float y4 = d4*rs*g1.x + t1.x, y5 = d5*rs*g1.y + t1.y;
            float y6 = d6*rs*g1.z + t1.z, y7 = d7*rs*g1.w + t1.w;
            if (l == 1) {
                y0 = fminf(fmaxf(y0, -100.f), 100.f); y1 = fminf(fmaxf(y1, -100.f), 100.f);
                y2 = fminf(fmaxf(y2, -100.f), 100.f); y3 = fminf(fmaxf(y3, -100.f), 100.f);
                y4 = fminf(fmaxf(y4, -100.f), 100.f); y5 = fminf(fmaxf(y5, -100.f), 100.f);
                y6 = fminf(fmaxf(y6, -100.f), 100.f); y7 = fminf(fmaxf(y7, -100.f), 100.f);
            }
            float4 o0 = {y0, y1, y2, y3}, o1 = {y4, y5, y6, y7};
            *(float4*)(hout + (size_t)gw * DD + lane * 8)     = o0;
            *(float4*)(hout + (size_t)gw * DD + lane * 8 + 4) = o1;
            if (hbf_out) {
                uint4 u;
                u.x = (unsigned)f2bf(y0) | ((unsigned)f2bf(y1) << 16);
                u.y = (unsigned)f2bf(y2) | ((unsigned)f2bf(y3) << 16);
                u.z = (unsigned)f2bf(y4) | ((unsigned)f2bf(y5) << 16);
                u.w = (unsigned)f2bf(y6) | ((unsigned)f2bf(y7) << 16);
                *(uint4*)(hbf_out + (size_t)gw * DD + lane * 8) = u;
            }
        }
        if (l == 0) GSYNC();          // uniform across all threads
    }
}

// ---------------------------------------------------------------------------
extern "C" void kernel_launch(void* const* d_in, const int* in_sizes, int n_in,
                              void* d_out, int out_size, void* d_ws, size_t ws_size,
                              hipStream_t stream)
{
    GnnParams prm;
    prm.h0    = (const float*)d_in[0];   // (4,96,512)
    prm.adj   = (const float*)d_in[1];   // (4,96,96)
    prm.W1a   = (const float*)d_in[2];   // (2,512,512)
    prm.W1b   = (const float*)d_in[3];   // (2,512,512)
    prm.b1    = (const float*)d_in[4];   // (2,512)
    prm.W2    = (const float*)d_in[5];   // (2,512,512)
    prm.b2    = (const float*)d_in[6];   // (2,512)
    prm.gamma = (const float*)d_in[7];   // (512)
    prm.beta  = (const float*)d_in[8];   // (512)
    prm.out   = (float*)d_out;           // (4,96,512)

    // never-rewrite workspace carve (~10.4 MB of >=256 MB)
    char* p = (char*)d_ws;
    prm.WT   = (unsigned short*)p;  p += 6u * DD * DD * 2;   // 3.00 MB
    prm.H0bf = (unsigned short*)p;  p += MROWS * DD * 2;     // 384 KB
    prm.H1bf = (unsigned short*)p;  p += MROWS * DD * 2;     // 384 KB
    prm.S0   = (unsigned short*)p;  p += MROWS * DD * 2;     // 384 KB
    prm.S1   = (unsigned short*)p;  p += MROWS * DD * 2;     // 384 KB
    prm.A0   = (float*)p;           p += MROWS * DD * 4;     // 768 KB
    prm.B0   = (float*)p;           p += MROWS * DD * 4;     // 768 KB
    prm.A1   = (float*)p;           p += MROWS * DD * 4;     // 768 KB
    prm.B1   = (float*)p;           p += MROWS * DD * 4;     // 768 KB
    prm.U0   = (float*)p;           p += MROWS * DD * 4;     // 768 KB
    prm.U1   = (float*)p;           p += MROWS * DD * 4;     // 768 KB
    prm.H1   = (float*)p;           p += MROWS * DD * 4;     // 768 KB
    prm.CNT  = (float*)p;                                    // 1.5 KB

    void* args[] = { (void*)&prm };
    hipLaunchCooperativeKernel((const void*)gnn_fused, dim3(GBLK), dim3(256),
                               args, 0, stream);
}

// Round 11
// 108.505 us; speedup vs baseline: 8.6189x; 8.6189x over previous
//
#include <hip/hip_runtime.h>

#define DD 512
#define MROWS 384            // 4 batches * 96 nodes
#define EPSF 1e-5f
#define INVN (1.0f / 96.0f)
#define YPAD 520             // S row stride (bf16/f32) -> 2-way banks on frags
#define UPAD 516             // U row stride (f32), 16B-aligned rows

typedef short short8v __attribute__((ext_vector_type(8)));
typedef float f32x4   __attribute__((ext_vector_type(4)));

// round-to-nearest-even f32 -> bf16 (raw ushort)
static __device__ __forceinline__ unsigned short f2bf(float x) {
    union { float f; unsigned int u; } v; v.f = x;
    unsigned int r = v.u + 0x7fffu + ((v.u >> 16) & 1u);
    return (unsigned short)(r >> 16);
}

// ---------------------------------------------------------------------------
// K1 (verbatim R5): z=0..5 -> transpose+convert weight mat z (l=z/3,
// {W1a,W1b,W2}) into WT[z] as bf16 [n][k]; z=6 -> h0 -> bf16 row-major.
// grid (16,16,7), block (32,8). 33-padded LDS tile: conflict-free transpose.
// ---------------------------------------------------------------------------
__global__ __launch_bounds__(256) void convert_w(
    const float* __restrict__ W1a, const float* __restrict__ W1b,
    const float* __restrict__ W2, const float* __restrict__ h0,
    unsigned short* __restrict__ WT, unsigned short* __restrict__ Hbf)
{
    const int tx = threadIdx.x, ty = threadIdx.y;
    const int z = blockIdx.z;
    const int c0 = blockIdx.x * 32, r0 = blockIdx.y * 32;

    if (z == 6) {
        if (r0 >= MROWS) return;
#pragma unroll
        for (int i = 0; i < 4; ++i) {
            const int r = r0 + ty + 8 * i;
            Hbf[(size_t)r * DD + c0 + tx] = f2bf(h0[(size_t)r * DD + c0 + tx]);
        }
        return;
    }

    __shared__ float t[32][33];
    const int l = z / 3, w = z % 3;
    const float* __restrict__ src =
        (w == 0 ? W1a : (w == 1 ? W1b : W2)) + (size_t)l * DD * DD;
    unsigned short* __restrict__ dst = WT + (size_t)z * DD * DD;

#pragma unroll
    for (int i = 0; i < 4; ++i)
        t[ty + 8 * i][tx] = src[(size_t)(r0 + ty + 8 * i) * DD + c0 + tx];
    __syncthreads();
#pragma unroll
    for (int i = 0; i < 4; ++i)
        dst[(size_t)(c0 + ty + 8 * i) * DD + r0 + tx] = f2bf(t[tx][ty + 8 * i]);
}

// ---------------------------------------------------------------------------
// K2 (verbatim R5): A' = Xbf @ Wa + b1 ; Bb = Xbf @ Wb  (fp32 out).
// One wave per 16x16 tile, K=512 -> 16 x mfma_f32_16x16x32_bf16.
// grid (6, 32, 2), block 256 (4 waves -> 4 consecutive m-tiles).
// ---------------------------------------------------------------------------
__global__ __launch_bounds__(256) void gemm_ab(
    const unsigned short* __restrict__ Xbf,
    const unsigned short* __restrict__ WaT,
    const unsigned short* __restrict__ WbT,
    const float* __restrict__ b1,
    float* __restrict__ outA, float* __restrict__ outB)
{
    const int lane = threadIdx.x & 63;
    const int wv   = threadIdx.x >> 6;
    const int m0   = (blockIdx.x * 4 + wv) * 16;
    const int n0   = blockIdx.y * 16;
    const int isB  = blockIdx.z;
    const unsigned short* __restrict__ Wt = isB ? WbT : WaT;

    const int lo = lane & 15, hi = lane >> 4;
    const unsigned short* ap = Xbf + (size_t)(m0 + lo) * DD + 8 * hi;
    const unsigned short* bp = Wt  + (size_t)(n0 + lo) * DD + 8 * hi;

    f32x4 acc = {0.f, 0.f, 0.f, 0.f};
#pragma unroll 4
    for (int k0 = 0; k0 < DD; k0 += 32) {
        const short8v a = *(const short8v*)(ap + k0);
        const short8v b = *(const short8v*)(bp + k0);
        acc = __builtin_amdgcn_mfma_f32_16x16x32_bf16(a, b, acc, 0, 0, 0);
    }

    const int col = n0 + lo;
    const float bias = isB ? 0.f : b1[col];
    float* __restrict__ outp = isB ? outB : outA;
    const int rb = m0 + 4 * hi;
#pragma unroll
    for (int i = 0; i < 4; ++i)
        outp[(size_t)(rb + i) * DD + col] = acc[i] + bias;
}

// ---------------------------------------------------------------------------
// K3 NEW (per layer): block owns 16 rows (b, i0) x all 512 cols.
//   (a) relusum: S[16][512] = sum_j mask*relu(A+Bb), j split across 2 halves
//       of 8 waves each, combined via LDS; S stored bf16 [16][YPAD].
//   (b) cnt[16] from mask LDS (wave 8, lanes 0-15, overlapped).
//   (c) msg GEMM: 32 col-tiles/16 waves, A-frag from S-LDS, B from W2T;
//       U = hin + INVN*(S@W2 + cnt*b2) -> LDS [16][UPAD].
//   (d) LayerNorm per wave-row + optional clip + optional bf16 emit.
// grid (24), 1024 threads (16 waves).
// ---------------------------------------------------------------------------
__global__ __launch_bounds__(1024) void layer_tail(
    const float* __restrict__ A, const float* __restrict__ Bb,
    const float* __restrict__ adj, const unsigned short* __restrict__ W2T,
    const float* __restrict__ b2l, const float* __restrict__ hin,
    const float* __restrict__ gamma, const float* __restrict__ beta,
    float* __restrict__ hout, unsigned short* __restrict__ hbf_out, int doClip)
{
    __shared__ float msk[16][96];                 // 6 KB
    __shared__ float cnt_s[16];
    __shared__ float Spart[16][YPAD];             // 33.3 KB (half1 partials)
    __shared__ unsigned short Sbf[16][YPAD];      // 16.6 KB
    __shared__ float U[16][UPAD];                 // 33 KB   (total ~89 KB)

    const int tid = threadIdx.x;
    const int blk = blockIdx.x;
    const int b   = blk / 6;
    const int i0  = (blk % 6) * 16;
    const int rb  = b * 96 + i0;                  // global row base

    // stage mask rows [i0, i0+16)  (1536 floats)
    for (int t = tid; t < 16 * 96; t += 1024)
        msk[t / 96][t % 96] = adj[(size_t)(rb + t / 96) * 96 + (t % 96)];
    __syncthreads();

    // cnt (wave 8, lanes 0-15; overlaps relusum, consumed after next sync)
    if (tid >= 512 && tid < 528) {
        const int q = tid - 512;
        float c = 0.f;
        for (int j = 0; j < 96; ++j) c += msk[q][j];
        cnt_s[q] = c;
    }

    // relusum: thread = (col d, half); half h sums j in [48h, 48h+48)
    {
        const int d    = tid & 511;
        const int half = tid >> 9;
        const int j0   = half * 48;
        float a16[16], s16[16];
#pragma unroll
        for (int q = 0; q < 16; ++q) {
            a16[q] = A[(size_t)(rb + q) * DD + d];
            s16[q] = 0.f;
        }
        const float* __restrict__ bbp = Bb + (size_t)(b * 96 + j0) * DD + d;
        for (int j = 0; j < 48; ++j) {
            const float bv = bbp[(size_t)j * DD];
#pragma unroll
            for (int q = 0; q < 16; ++q)
                s16[q] = fmaf(msk[q][j0 + j], fmaxf(a16[q] + bv, 0.f), s16[q]);
        }
        if (half == 1) {
#pragma unroll
            for (int q = 0; q < 16; ++q) Spart[q][d] = s16[q];
        }
        __syncthreads();
        if (half == 0) {
#pragma unroll
            for (int q = 0; q < 16; ++q)
                Sbf[q][d] = f2bf(s16[q] + Spart[q][d]);
        }
    }
    __syncthreads();

    // msg GEMM: wave wv -> col-tiles n0 = (wv*2+i)*16
    const int lane = tid & 63;
    const int wv   = tid >> 6;
    const int lo = lane & 15, hi = lane >> 4;
#pragma unroll
    for (int i = 0; i < 2; ++i) {
        const int n0 = (wv * 2 + i) * 16;
        const unsigned short* bp = W2T + (size_t)(n0 + lo) * DD + 8 * hi;
        f32x4 acc = {0.f, 0.f, 0.f, 0.f};
#pragma unroll 4
        for (int k0 = 0; k0 < DD; k0 += 32) {
            const short8v av = *(const short8v*)&Sbf[lo][8 * hi + k0];
            const short8v bv = *(const short8v*)(bp + k0);
            acc = __builtin_amdgcn_mfma_f32_16x16x32_bf16(av, bv, acc, 0, 0, 0);
        }
        const int col = n0 + lo;
        const float b2c = b2l[col];
#pragma unroll
        for (int q = 0; q < 4; ++q) {
            const int rr = 4 * hi + q;
            U[rr][col] = hin[(size_t)(rb + rr) * DD + col]
                       + INVN * acc[q] + (cnt_s[rr] * INVN) * b2c;
        }
    }
    __syncthreads();

    // LayerNorm: wave wv -> row rr = wv (shfl-only, R5-proven math)
    {
        const int rr = wv;
        const int r  = rb + rr;
        const float4 x0 = *(const float4*)&U[rr][lane * 8];
        const float4 x1 = *(const float4*)&U[rr][lane * 8 + 4];
        float s = x0.x + x0.y + x0.z + x0.w + x1.x + x1.y + x1.z + x1.w;
#pragma unroll
        for (int off = 32; off > 0; off >>= 1) s += __shfl_xor(s, off);
        const float mu = s * (1.0f / 512.0f);
        const float d0 = x0.x - mu, d1 = x0.y - mu, d2 = x0.z - mu, d3 = x0.w - mu;
        const float d4 = x1.x - mu, d5 = x1.y - mu, d6 = x1.z - mu, d7 = x1.w - mu;
        float q = d0*d0 + d1*d1 + d2*d2 + d3*d3 + d4*d4 + d5*d5 + d6*d6 + d7*d7;
#pragma unroll
        for (int off = 32; off > 0; off >>= 1) q += __shfl_xor(q, off);
        const float rs = rsqrtf(q * (1.0f / 512.0f) + EPSF);

        const float4 g0 = *(const float4*)(gamma + lane * 8);
        const float4 g1 = *(const float4*)(gamma + lane * 8 + 4);
        const float4 t0 = *(const float4*)(beta + lane * 8);
        const float4 t1 = *(const float4*)(beta + lane * 8 + 4);
        float y0 = d0*rs*g0.x + t0.x, y1 = d1*rs*g0.y + t0.y;
        float y2 = d2*rs*g0.z + t0.z, y3 = d3*rs*g0.w + t0.w;
        float y4 = d4*rs*g1.x + t1.x, y5 = d5*rs*g1.y + t1.y;
        float y6 = d6*rs*g1.z + t1.z, y7 = d7*rs*g1.w + t1.w;
        if (doClip) {
            y0 = fminf(fmaxf(y0, -100.f), 100.f); y1 = fminf(fmaxf(y1, -100.f), 100.f);
            y2 = fminf(fmaxf(y2, -100.f), 100.f); y3 = fminf(fmaxf(y3, -100.f), 100.f);
            y4 = fminf(fmaxf(y4, -100.f), 100.f); y5 = fminf(fmaxf(y5, -100.f), 100.f);
            y6 = fminf(fmaxf(y6, -100.f), 100.f); y7 = fminf(fmaxf(y7, -100.f), 100.f);
        }
        float4 o0 = {y0, y1, y2, y3}, o1 = {y4, y5, y6, y7};
        *(float4*)(hout + (size_t)r * DD + lane * 8)     = o0;
        *(float4*)(hout + (size_t)r * DD + lane * 8 + 4) = o1;
        if (hbf_out) {
            uint4 u;
            u.x = (unsigned)f2bf(y0) | ((unsigned)f2bf(y1) << 16);
            u.y = (unsigned)f2bf(y2) | ((unsigned)f2bf(y3) << 16);
            u.z = (unsigned)f2bf(y4) | ((unsigned)f2bf(y5) << 16);
            u.w = (unsigned)f2bf(y6) | ((unsigned)f2bf(y7) << 16);
            *(uint4*)(hbf_out + (size_t)r * DD + lane * 8) = u;
        }
    }
}

// ---------------------------------------------------------------------------
extern "C" void kernel_launch(void* const* d_in, const int* in_sizes, int n_in,
                              void* d_out, int out_size, void* d_ws, size_t ws_size,
                              hipStream_t stream)
{
    const float* h0    = (const float*)d_in[0];  // (4,96,512)
    const float* adj   = (const float*)d_in[1];  // (4,96,96)
    const float* W1a   = (const float*)d_in[2];  // (2,512,512)
    const float* W1b   = (const float*)d_in[3];  // (2,512,512)
    const float* b1    = (const float*)d_in[4];  // (2,512)
    const float* W2    = (const float*)d_in[5];  // (2,512,512)
    const float* b2    = (const float*)d_in[6];  // (2,512)
    const float* gamma = (const float*)d_in[7];  // (512)
    const float* beta  = (const float*)d_in[8];  // (512)
    float* out = (float*)d_out;                  // (4,96,512)

    char* p = (char*)d_ws;
    unsigned short* WT   = (unsigned short*)p;  p += 6u * DD * DD * 2;  // 3.00 MB
    unsigned short* Hbf  = (unsigned short*)p;  p += MROWS * DD * 2;    // 384 KB
    unsigned short* H1bf = (unsigned short*)p;  p += MROWS * DD * 2;    // 384 KB
    float* A   = (float*)p;  p += MROWS * DD * 4;                       // 768 KB
    float* Bb  = (float*)p;  p += MROWS * DD * 4;                       // 768 KB
    float* H1  = (float*)p;  p += MROWS * DD * 4;                       // 768 KB

    // C: weight transposes + h0 -> bf16
    convert_w<<<dim3(16, 16, 7), dim3(32, 8), 0, stream>>>(W1a, W1b, W2, h0, WT, Hbf);

    for (int l = 0; l < 2; ++l) {
        const unsigned short* waT = WT + (size_t)(l * 3 + 0) * DD * DD;
        const unsigned short* wbT = WT + (size_t)(l * 3 + 1) * DD * DD;
        const unsigned short* w2T = WT + (size_t)(l * 3 + 2) * DD * DD;
        const unsigned short* xbf = (l == 0) ? Hbf : H1bf;
        const float* hin = (l == 0) ? h0 : H1;
        float* hout = (l == 0) ? H1 : out;
        unsigned short* hbf_next = (l == 0) ? H1bf : nullptr;

        gemm_ab<<<dim3(6, 32, 2), 256, 0, stream>>>(
            xbf, waT, wbT, b1 + (size_t)l * DD, A, Bb);
        layer_tail<<<dim3(24), 1024, 0, stream>>>(
            A, Bb, adj, w2T, b2 + (size_t)l * DD, hin, gamma, beta, hout,
            hbf_next, l == 1);
    }
}